// Round 2
// baseline (110.789 us; speedup 1.0000x reference)
//
#include <hip/hip_runtime.h>

#define B_SZ 16384
#define D_IN 65
#define N_SP 129

#define GRID 1024
#define BLOCK 256
#define QSTRIDE 68

// index into main_w for quadratic pair (i<j), N=129: N + i*(2N-i-1)/2 + (j-i-1)
__device__ __forceinline__ int qidx(int i, int j) {
  return N_SP + i * (2 * N_SP - i - 1) / 2 + (j - i - 1);
}

__device__ __forceinline__ float rdl(float v, int l) {
  return __int_as_float(__builtin_amdgcn_readlane(__float_as_int(v), l));
}

// tanh(x) = 1 - 2/(e^{2x}+1): monotone, stable both tails, no cancellation
__device__ __forceinline__ float fast_tanh(float x) {
  float xc = fminf(fmaxf(x, -15.f), 15.f);
  float e = __expf(2.f * xc);
  return 1.f - 2.f / (e + 1.f);
}

__global__ __launch_bounds__(BLOCK, 4) void main_kernel(
    const float* __restrict__ inps, const float* __restrict__ tw,
    const float* __restrict__ tb, const float* __restrict__ mw,
    float* __restrict__ out, float* __restrict__ ws) {
  __shared__ float s_tw[4352];   // 64 rows, stride 68 (16B aligned, b128 conflict-free)
  __shared__ float s_qtt[4352];  // symmetrized t-t block, stride 68
  __shared__ float s_qxy[64], s_qyt[64], s_lint[64], s_tb[64];
  __shared__ float s_red[8];

  const int tid = threadIdx.x;
  // Stage thresh_w and symmetrized Qtt directly from global (no setup kernel).
  for (int idx = tid; idx < 4352; idx += BLOCK) {
    int i = idx / QSTRIDE, d = idx - i * QSTRIDE;
    s_tw[idx] = (d < 65) ? tw[i * 65 + d] : 0.f;
    float v = 0.f;
    if (d < 64 && d != i) {
      int a = i < d ? i : d, b = i < d ? d : i;
      v = mw[qidx(65 + a, 65 + b)];
    }
    s_qtt[idx] = v;
  }
  if (tid < 64) {
    s_qxy[tid] = mw[qidx(tid, 64)];        // Q[x_i, y]
    s_qyt[tid] = mw[qidx(64, 65 + tid)];   // Q[y, t_k] (contiguous)
    s_lint[tid] = mw[65 + tid];            // linear t coeffs
    s_tb[tid] = tb[tid];
  }
  __syncthreads();

  const int lane = tid & 63;
  const int wave = (blockIdx.x * BLOCK + tid) >> 6;  // 0..4095 == group id
  const int b0 = wave << 2;
  const int b0u = __builtin_amdgcn_readfirstlane(b0);  // force wave-uniform (SGPR)

  const float liny = mw[64];
  const float twy = s_tw[lane * QSTRIDE + 64];
  const float qxy = s_qxy[lane], qyt = s_qyt[lane];
  const float lint = s_lint[lane], tbv = s_tb[lane];
  const int qxt_base = qidx(lane, 65);  // Qxt[lane][k] = mw[qxt_base + k], contiguous

  float xv[4], yv[4], acc[4];
  const float* xr[4];
#pragma unroll
  for (int r = 0; r < 4; r++) {
    xr[r] = inps + (b0u + r) * D_IN;  // uniform base -> scalar loads below
    xv[r] = xr[r][lane];              // per-lane copy for the x_i-weighted terms
    yv[r] = xr[r][64];
    acc[r] = tbv;
  }
  // w[a] (a = lane) over d=0..63 with x from uniform (scalar) loads;
  // y-term split out: w1 = acc + twy*y, w2 = acc - twy*y
#pragma unroll
  for (int d4 = 0; d4 < 64; d4 += 4) {
    const float4 w = *(const float4*)&s_tw[lane * QSTRIDE + d4];
#pragma unroll
    for (int r = 0; r < 4; r++) {
      acc[r] += w.x * xr[r][d4 + 0];
      acc[r] += w.y * xr[r][d4 + 1];
      acc[r] += w.z * xr[r][d4 + 2];
      acc[r] += w.w * xr[r][d4 + 3];
    }
  }

  float dt[4], st[4];
  float pint = 0.f, pneut = 0.f;
#pragma unroll
  for (int r = 0; r < 4; r++) {
    float w1 = acc[r] + twy * yv[r];
    float w2 = acc[r] - twy * yv[r];
    float t1 = fast_tanh(w1), t2 = fast_tanh(w2);
    dt[r] = t1 - t2;
    st[r] = t1 + t2;
    float a1 = 1.f - t1 * t1, a2 = 1.f - t2 * t2;
    pint += a1 * a1 + a2 * a2;
    float nv = t2 * w2 - t1 * w1;
    pneut += nv * nv;
  }

  float rxt[4] = {0.f, 0.f, 0.f, 0.f}, rtt[4] = {0.f, 0.f, 0.f, 0.f};
#pragma unroll
  for (int k4 = 0; k4 < 64; k4 += 4) {
    const float4 qt = *(const float4*)&s_qtt[lane * QSTRIDE + k4];
    const float qx0 = mw[qxt_base + k4 + 0];
    const float qx1 = mw[qxt_base + k4 + 1];
    const float qx2 = mw[qxt_base + k4 + 2];
    const float qx3 = mw[qxt_base + k4 + 3];
#pragma unroll
    for (int r = 0; r < 4; r++) {
      float d0 = rdl(dt[r], k4 + 0), d1 = rdl(dt[r], k4 + 1);
      float d2 = rdl(dt[r], k4 + 2), d3 = rdl(dt[r], k4 + 3);
      rxt[r] += qx0 * d0 + qx1 * d1 + qx2 * d2 + qx3 * d3;
      rtt[r] += qt.x * d0 + qt.y * d1 + qt.z * d2 + qt.w * d3;
    }
  }

#pragma unroll
  for (int r = 0; r < 4; r++) {
    float c = 2.f * yv[r] * xv[r] * qxy + xv[r] * rxt[r] +
              yv[r] * st[r] * qyt + 0.5f * st[r] * rtt[r] + lint * dt[r];
#pragma unroll
    for (int off = 32; off > 0; off >>= 1) c += __shfl_down(c, off);
    if (lane == 0) out[b0 + r] = 1.f + 2.f * yv[r] * liny + c;
  }

  // per-block penalty partials -> ws (atomic-free; reduced by reduce_kernel)
#pragma unroll
  for (int off = 32; off > 0; off >>= 1) {
    pint += __shfl_down(pint, off);
    pneut += __shfl_down(pneut, off);
  }
  const int widx = tid >> 6;
  if (lane == 0) {
    s_red[widx] = pint;
    s_red[4 + widx] = pneut;
  }
  __syncthreads();
  if (tid == 0) {
    ws[blockIdx.x] = s_red[0] + s_red[1] + s_red[2] + s_red[3];
    ws[GRID + blockIdx.x] = s_red[4] + s_red[5] + s_red[6] + s_red[7];
  }
}

__global__ __launch_bounds__(1024) void reduce_kernel(const float* __restrict__ ws,
                                                      float* __restrict__ out) {
  __shared__ float s[32];
  const int tid = threadIdx.x;
  float a = ws[tid];
  float b = ws[GRID + tid];
#pragma unroll
  for (int off = 32; off > 0; off >>= 1) {
    a += __shfl_down(a, off);
    b += __shfl_down(b, off);
  }
  const int w = tid >> 6, lane = tid & 63;
  if (lane == 0) { s[w] = a; s[16 + w] = b; }
  __syncthreads();
  if (tid == 0) {
    float sa = 0.f, sb = 0.f;
#pragma unroll
    for (int i = 0; i < 16; i++) { sa += s[i]; sb += s[16 + i]; }
    out[B_SZ] = sa * (1.f / 300.f);
    out[B_SZ + 1] = sb;
  }
}

extern "C" void kernel_launch(void* const* d_in, const int* in_sizes, int n_in,
                              void* d_out, int out_size, void* d_ws, size_t ws_size,
                              hipStream_t stream) {
  const float* inps = (const float*)d_in[0];
  const float* tw   = (const float*)d_in[1];
  const float* tb   = (const float*)d_in[2];
  const float* mw   = (const float*)d_in[3];
  float* out = (float*)d_out;
  float* ws  = (float*)d_ws;
  main_kernel<<<GRID, BLOCK, 0, stream>>>(inps, tw, tb, mw, out, ws);
  reduce_kernel<<<1, 1024, 0, stream>>>(ws, out);
}

// Round 3
// 88.394 us; speedup vs baseline: 1.2533x; 1.2533x over previous
//
#include <hip/hip_runtime.h>

#define B_SZ 16384
#define D_IN 65
#define N_SP 129

#define GRID 1024
#define BLOCK 256
#define QSTRIDE 68

// ws layout (floats)
#define WS_QXT 0
#define WS_QTT 4352
#define WS_TW  8704
#define WS_QXY 13056
#define WS_QYT 13120
#define WS_LINT 13184
#define WS_LINY 13248
#define WS_P1 14336
#define WS_P2 15360

// index into main_w for quadratic pair (i<j), N=129: N + i*(2N-i-1)/2 + (j-i-1)
__device__ __forceinline__ int qidx(int i, int j) {
  return N_SP + i * (2 * N_SP - i - 1) / 2 + (j - i - 1);
}

__device__ __forceinline__ float rdl(float v, int l) {
  return __int_as_float(__builtin_amdgcn_readlane(__float_as_int(v), l));
}

// tanh(x) = 1 - 2/(e^{2x}+1): monotone, stable both tails, no cancellation
__device__ __forceinline__ float fast_tanh(float x) {
  float xc = fminf(fmaxf(x, -15.f), 15.f);
  float e = __expf(2.f * xc);
  return 1.f - 2.f / (e + 1.f);
}

// Gather/symmetrize/pad all coefficient tables once -> ws (contiguous, stride-68)
__global__ void setup_kernel(const float* __restrict__ mw, const float* __restrict__ tw,
                             float* __restrict__ ws) {
  int t = blockIdx.x * blockDim.x + threadIdx.x;
  if (t < 4352) {
    int i = t / QSTRIDE, k = t - i * QSTRIDE;
    ws[WS_QXT + t] = (k < 64) ? mw[qidx(i, 65 + k)] : 0.f;
  } else if (t < 8704) {
    int r = t - 4352;
    int j = r / QSTRIDE, k = r - j * QSTRIDE;
    float v = 0.f;
    if (k < 64 && k != j) {
      int a = j < k ? j : k, b = j < k ? k : j;
      v = mw[qidx(65 + a, 65 + b)];
    }
    ws[WS_QTT + r] = v;
  } else if (t < 13056) {
    int r = t - 8704;
    int i = r / QSTRIDE, d = r - i * QSTRIDE;
    ws[WS_TW + r] = (d < 65) ? tw[i * 65 + d] : 0.f;
  } else if (t < 13120) {
    ws[WS_QXY + (t - 13056)] = mw[qidx(t - 13056, 64)];
  } else if (t < 13184) {
    ws[WS_QYT + (t - 13120)] = mw[qidx(64, 65 + (t - 13120))];
  } else if (t < 13248) {
    ws[WS_LINT + (t - 13184)] = mw[65 + (t - 13184)];
  } else if (t == 13248) {
    ws[WS_LINY] = mw[64];
  }
}

__global__ __launch_bounds__(BLOCK, 2) void main_kernel(
    const float* __restrict__ inps, const float* __restrict__ tb,
    const float* __restrict__ ws, float* __restrict__ out) {
  __shared__ float4 s_buf4[3264];  // qxt | qtt | tw, each 64 rows x stride 68
  __shared__ float s_red[8];
  float* s_buf = (float*)s_buf4;
  const float* s_qxt = s_buf;
  const float* s_qtt = s_buf + 4352;
  const float* s_tw  = s_buf + 8704;

  const int tid = threadIdx.x;
  const int lane = tid & 63;
  const int wave = (blockIdx.x * BLOCK + tid) >> 6;  // 0..4095 == group id
  const int b0 = wave << 2;

  // Prefetch this wave's 4 rows (global latency overlaps the LDS fill below)
  float xv[4], yv[4];
#pragma unroll
  for (int r = 0; r < 4; r++) {
    xv[r] = inps[(b0 + r) * D_IN + lane];
    yv[r] = inps[(b0 + r) * D_IN + 64];
  }
  const float qxy = ws[WS_QXY + lane], qyt = ws[WS_QYT + lane];
  const float lint = ws[WS_LINT + lane], liny = ws[WS_LINY];
  const float tbv = tb[lane];

  // Contiguous float4 copy ws -> LDS (no divides, fully coalesced)
  const float4* wsv = (const float4*)ws;
  for (int i = tid; i < 3264; i += BLOCK) s_buf4[i] = wsv[i];
  __syncthreads();

  const float twy = s_tw[lane * QSTRIDE + 64];

  // w[a] (a=lane): split into 2 FMA chains/row for ILP; y-term folded after
  float a0[4], a1[4];
#pragma unroll
  for (int r = 0; r < 4; r++) { a0[r] = tbv; a1[r] = 0.f; }
#pragma unroll
  for (int d8 = 0; d8 < 64; d8 += 8) {
    const float4 w0 = *(const float4*)&s_tw[lane * QSTRIDE + d8];
    const float4 w1 = *(const float4*)&s_tw[lane * QSTRIDE + d8 + 4];
#pragma unroll
    for (int r = 0; r < 4; r++) {
      a0[r] += w0.x * rdl(xv[r], d8 + 0);
      a0[r] += w0.y * rdl(xv[r], d8 + 1);
      a0[r] += w0.z * rdl(xv[r], d8 + 2);
      a0[r] += w0.w * rdl(xv[r], d8 + 3);
      a1[r] += w1.x * rdl(xv[r], d8 + 4);
      a1[r] += w1.y * rdl(xv[r], d8 + 5);
      a1[r] += w1.z * rdl(xv[r], d8 + 6);
      a1[r] += w1.w * rdl(xv[r], d8 + 7);
    }
  }

  float dt[4], st[4];
  float pint = 0.f, pneut = 0.f;
#pragma unroll
  for (int r = 0; r < 4; r++) {
    float acc = a0[r] + a1[r];
    float w1v = acc + twy * yv[r];
    float w2v = acc - twy * yv[r];
    float t1 = fast_tanh(w1v), t2 = fast_tanh(w2v);
    dt[r] = t1 - t2;
    st[r] = t1 + t2;
    float q1 = 1.f - t1 * t1, q2 = 1.f - t2 * t2;
    pint += q1 * q1 + q2 * q2;
    float nv = t2 * w2v - t1 * w1v;
    pneut += nv * nv;
  }

  float rxt[4] = {0.f, 0.f, 0.f, 0.f}, rtt[4] = {0.f, 0.f, 0.f, 0.f};
#pragma unroll
  for (int k4 = 0; k4 < 64; k4 += 4) {
    const float4 qx = *(const float4*)&s_qxt[lane * QSTRIDE + k4];
    const float4 qt = *(const float4*)&s_qtt[lane * QSTRIDE + k4];
#pragma unroll
    for (int r = 0; r < 4; r++) {
      float d0 = rdl(dt[r], k4 + 0), d1 = rdl(dt[r], k4 + 1);
      float d2 = rdl(dt[r], k4 + 2), d3 = rdl(dt[r], k4 + 3);
      rxt[r] += qx.x * d0 + qx.y * d1 + qx.z * d2 + qx.w * d3;
      rtt[r] += qt.x * d0 + qt.y * d1 + qt.z * d2 + qt.w * d3;
    }
  }

#pragma unroll
  for (int r = 0; r < 4; r++) {
    float c = 2.f * yv[r] * xv[r] * qxy + xv[r] * rxt[r] +
              yv[r] * st[r] * qyt + 0.5f * st[r] * rtt[r] + lint * dt[r];
#pragma unroll
    for (int off = 32; off > 0; off >>= 1) c += __shfl_down(c, off);
    if (lane == 0) out[b0 + r] = 1.f + 2.f * yv[r] * liny + c;
  }

  // per-block penalty partials -> ws (atomic-free)
#pragma unroll
  for (int off = 32; off > 0; off >>= 1) {
    pint += __shfl_down(pint, off);
    pneut += __shfl_down(pneut, off);
  }
  const int widx = tid >> 6;
  if (lane == 0) {
    s_red[widx] = pint;
    s_red[4 + widx] = pneut;
  }
  __syncthreads();
  if (tid == 0) {
    float* wsm = (float*)ws;
    wsm[WS_P1 + blockIdx.x] = s_red[0] + s_red[1] + s_red[2] + s_red[3];
    wsm[WS_P2 + blockIdx.x] = s_red[4] + s_red[5] + s_red[6] + s_red[7];
  }
}

__global__ __launch_bounds__(1024) void reduce_kernel(const float* __restrict__ ws,
                                                      float* __restrict__ out) {
  __shared__ float s[32];
  const int tid = threadIdx.x;
  float a = ws[WS_P1 + tid];
  float b = ws[WS_P2 + tid];
#pragma unroll
  for (int off = 32; off > 0; off >>= 1) {
    a += __shfl_down(a, off);
    b += __shfl_down(b, off);
  }
  const int w = tid >> 6, lane = tid & 63;
  if (lane == 0) { s[w] = a; s[16 + w] = b; }
  __syncthreads();
  if (tid == 0) {
    float sa = 0.f, sb = 0.f;
#pragma unroll
    for (int i = 0; i < 16; i++) { sa += s[i]; sb += s[16 + i]; }
    out[B_SZ] = sa * (1.f / 300.f);
    out[B_SZ + 1] = sb;
  }
}

extern "C" void kernel_launch(void* const* d_in, const int* in_sizes, int n_in,
                              void* d_out, int out_size, void* d_ws, size_t ws_size,
                              hipStream_t stream) {
  const float* inps = (const float*)d_in[0];
  const float* tw   = (const float*)d_in[1];
  const float* tb   = (const float*)d_in[2];
  const float* mw   = (const float*)d_in[3];
  float* out = (float*)d_out;
  float* ws  = (float*)d_ws;
  setup_kernel<<<52, 256, 0, stream>>>(mw, tw, ws);
  main_kernel<<<GRID, BLOCK, 0, stream>>>(inps, tb, ws, out);
  reduce_kernel<<<1, 1024, 0, stream>>>(ws, out);
}

// Round 4
// 73.246 us; speedup vs baseline: 1.5126x; 1.2068x over previous
//
#include <hip/hip_runtime.h>

#define B_SZ 16384
#define N_SP 129

typedef _Float16 half8 __attribute__((ext_vector_type(8)));
typedef float float4v __attribute__((ext_vector_type(4)));

// ws layout:
//   bytes [0, 24576): 24 B-fragments, each 64 lanes x 8 f16 (16B/lane).
//     frag id: tw = t*4+g (t=k-tile 0..1, g=n-group 0..3); qxt = 8+t*4+g; qtt = 16+t*4+g
//     element order: ((frag*64 + lane)*8 + j) halves
//   floats from WS_F32_BASE: twy[64] qxy[64] qyt[64] lint[64] liny[1] p1[256] p2[256]
#define WS_F32_BASE 6144
#define WS_TWY  (WS_F32_BASE)
#define WS_QXY  (WS_F32_BASE + 64)
#define WS_QYT  (WS_F32_BASE + 128)
#define WS_LINT (WS_F32_BASE + 192)
#define WS_LINY (WS_F32_BASE + 256)
#define WS_P1   (WS_F32_BASE + 320)
#define WS_P2   (WS_F32_BASE + 576)

// index into main_w for quadratic pair (i<j), N=129: N + i*(2N-i-1)/2 + (j-i-1)
__device__ __forceinline__ int qidx(int i, int j) {
  return N_SP + i * (2 * N_SP - i - 1) / 2 + (j - i - 1);
}

// tanh(x) = 1 - 2/(e^{2x}+1): monotone, stable both tails
__device__ __forceinline__ float fast_tanh(float x) {
  float xc = fminf(fmaxf(x, -15.f), 15.f);
  float e = __expf(2.f * xc);
  return 1.f - 2.f / (e + 1.f);
}

__global__ void setup_kernel(const float* __restrict__ mw, const float* __restrict__ tw,
                             float* __restrict__ wsf) {
  int t = blockIdx.x * blockDim.x + threadIdx.x;
  if (t < 12288) {
    int frag = t >> 9;          // /512 halves per frag
    int e = t & 511;
    int lane = e >> 3, j = e & 7;
    int tbl = frag >> 3;        // 0=tw 1=qxt 2=qtt
    int tg = frag & 7;
    int kt = tg >> 2, g = tg & 3;
    int k = kt * 32 + (lane >> 4) * 8 + j;   // K index (d or u), 0..63
    int n = (lane & 15) + 16 * g;            // N index (unit or i), 0..63
    float v;
    if (tbl == 0) {
      v = tw[n * 65 + k];                    // B[k][n] = tw[n][k]
    } else if (tbl == 1) {
      v = mw[qidx(n, 65 + k)];               // Qxt[i=n][u=k]
    } else {
      v = 0.f;
      if (n != k) {
        int a = n < k ? n : k, b = n < k ? k : n;
        v = mw[qidx(65 + a, 65 + b)];        // Qtt_sym[j'=n][u=k]
      }
    }
    ((_Float16*)wsf)[t] = (_Float16)v;
  } else if (t < 12352) {
    int u = t - 12288; wsf[WS_TWY + u] = tw[u * 65 + 64];
  } else if (t < 12416) {
    int i = t - 12352; wsf[WS_QXY + i] = mw[qidx(i, 64)];
  } else if (t < 12480) {
    int u = t - 12416; wsf[WS_QYT + u] = mw[qidx(64, 65 + u)];
  } else if (t < 12544) {
    int u = t - 12480; wsf[WS_LINT + u] = mw[65 + u];
  } else if (t == 12544) {
    wsf[WS_LINY] = mw[64];
  }
}

__global__ void main_kernel(const float* __restrict__ inps, const float* __restrict__ tb,
                            float* __restrict__ wsf, float* __restrict__ out) {
  __shared__ __align__(16) float s_x[4 * 1056];   // per-wave flat copy of 16 rows x 65
  __shared__ __align__(16) float s_dt[4 * 1088];  // per-wave dt[16 rows][stride 68]
  __shared__ float s_red[8];

  const int tid = threadIdx.x;
  const int l = tid & 63, wib = tid >> 6;
  const int wave = (blockIdx.x << 2) + wib;   // 0..1023
  const int b0 = wave << 4;                    // 16 rows per wave
  const int q = l >> 4, m = l & 15;

  float* xw = s_x + wib * 1056;
  float* dtw = s_dt + wib * 1088;

  // flat coalesced copy of this wave's 16 rows (1040 floats)
  const float* src = inps + b0 * 65;
#pragma unroll
  for (int t = 0; t < 16; t++) xw[t * 64 + l] = src[t * 64 + l];
  if (l < 16) xw[1024 + l] = src[1024 + l];

  const half8* fragh = (const half8*)wsf;

  // per-lane small tables: u/i index = m + 16g
  float twyv[4], tbv[4], qxyv[4], qytv[4], lintv[4];
#pragma unroll
  for (int g = 0; g < 4; g++) {
    int u = m + 16 * g;
    twyv[g] = wsf[WS_TWY + u];
    tbv[g] = tb[u];
    qxyv[g] = wsf[WS_QXY + u];
    qytv[g] = wsf[WS_QYT + u];
    lintv[g] = wsf[WS_LINT + u];
  }
  const float liny = wsf[WS_LINY];

  // A-frags of x: lane holds row m, k = t*32 + q*8 + j (d index, 0..63)
  half8 ax[2];
#pragma unroll
  for (int t = 0; t < 2; t++) {
    const float* xp = xw + m * 65 + t * 32 + q * 8;
#pragma unroll
    for (int j = 0; j < 8; j++) ax[t][j] = (_Float16)xp[j];
  }

  // matvec: acc[g] = X[16x64] . twT -> w_pre in C-layout (row=q*4+reg, unit=m+16g)
  float4v acc[4];
#pragma unroll
  for (int g = 0; g < 4; g++) { acc[g][0] = 0.f; acc[g][1] = 0.f; acc[g][2] = 0.f; acc[g][3] = 0.f; }
#pragma unroll
  for (int g = 0; g < 4; g++)
#pragma unroll
    for (int t = 0; t < 2; t++)
      acc[g] = __builtin_amdgcn_mfma_f32_16x16x32_f16(ax[t], fragh[(t * 4 + g) * 64 + l], acc[g], 0, 0, 0);

  // epilogue 1: tanh pair, penalties, dt/st; dt also -> LDS for A-relayout
  float yv[4];
#pragma unroll
  for (int r = 0; r < 4; r++) yv[r] = xw[(q * 4 + r) * 65 + 64];
  float dtv[4][4], stv[4][4];
  float pint = 0.f, pneut = 0.f;
#pragma unroll
  for (int g = 0; g < 4; g++)
#pragma unroll
    for (int r = 0; r < 4; r++) {
      float wpre = acc[g][r] + tbv[g];
      float w1 = wpre + twyv[g] * yv[r];
      float w2 = wpre - twyv[g] * yv[r];
      float t1 = fast_tanh(w1), t2 = fast_tanh(w2);
      float dt = t1 - t2, st = t1 + t2;
      dtv[g][r] = dt; stv[g][r] = st;
      float a1 = 1.f - t1 * t1, a2 = 1.f - t2 * t2;
      pint += a1 * a1 + a2 * a2;
      float nv = t2 * w2 - t1 * w1;
      pneut += nv * nv;
      dtw[(q * 4 + r) * 68 + m + 16 * g] = dt;  // same-wave LDS: DS pipe is in-order
    }

  // A-frags of dt: lane holds row m, k = u = t*32 + q*8 + j
  half8 adt[2];
#pragma unroll
  for (int t = 0; t < 2; t++) {
    const float* dp = dtw + m * 68 + t * 32 + q * 8;
#pragma unroll
    for (int j = 0; j < 8; j++) adt[t][j] = (_Float16)dp[j];
  }

  // quad: rxt = dt . QxtT, rtt = dt . QttT (C-layout: row=q*4+reg, i=m+16g)
  float4v rxt[4], rtt[4];
#pragma unroll
  for (int g = 0; g < 4; g++) {
    rxt[g][0] = 0.f; rxt[g][1] = 0.f; rxt[g][2] = 0.f; rxt[g][3] = 0.f;
    rtt[g][0] = 0.f; rtt[g][1] = 0.f; rtt[g][2] = 0.f; rtt[g][3] = 0.f;
  }
#pragma unroll
  for (int g = 0; g < 4; g++)
#pragma unroll
    for (int t = 0; t < 2; t++) {
      rxt[g] = __builtin_amdgcn_mfma_f32_16x16x32_f16(adt[t], fragh[(8 + t * 4 + g) * 64 + l], rxt[g], 0, 0, 0);
      rtt[g] = __builtin_amdgcn_mfma_f32_16x16x32_f16(adt[t], fragh[(16 + t * 4 + g) * 64 + l], rtt[g], 0, 0, 0);
    }

  // final assembly: per (row=q*4+r, i=m+16g) contribution, reduce over g then lanes m
  float creg[4] = {0.f, 0.f, 0.f, 0.f};
#pragma unroll
  for (int g = 0; g < 4; g++)
#pragma unroll
    for (int r = 0; r < 4; r++) {
      float xv = xw[(q * 4 + r) * 65 + m + 16 * g];
      creg[r] += xv * (2.f * yv[r] * qxyv[g] + rxt[g][r])
               + yv[r] * stv[g][r] * qytv[g]
               + 0.5f * stv[g][r] * rtt[g][r]
               + lintv[g] * dtv[g][r];
    }
#pragma unroll
  for (int r = 0; r < 4; r++) {
    float c = creg[r];
    c += __shfl_xor(c, 1); c += __shfl_xor(c, 2);
    c += __shfl_xor(c, 4); c += __shfl_xor(c, 8);
    if (m == 0) out[b0 + q * 4 + r] = 1.f + 2.f * yv[r] * liny + c;
  }

  // penalties: wave reduce -> block reduce -> per-block partials in ws
#pragma unroll
  for (int off = 1; off < 64; off <<= 1) {
    pint += __shfl_xor(pint, off);
    pneut += __shfl_xor(pneut, off);
  }
  if (l == 0) { s_red[wib] = pint; s_red[4 + wib] = pneut; }
  __syncthreads();
  if (tid == 0) {
    wsf[WS_P1 + blockIdx.x] = s_red[0] + s_red[1] + s_red[2] + s_red[3];
    wsf[WS_P2 + blockIdx.x] = s_red[4] + s_red[5] + s_red[6] + s_red[7];
  }
}

__global__ __launch_bounds__(256) void reduce_kernel(const float* __restrict__ wsf,
                                                     float* __restrict__ out) {
  __shared__ float s[8];
  const int tid = threadIdx.x;
  float a = wsf[WS_P1 + tid];
  float b = wsf[WS_P2 + tid];
#pragma unroll
  for (int off = 1; off < 64; off <<= 1) {
    a += __shfl_xor(a, off);
    b += __shfl_xor(b, off);
  }
  const int w = tid >> 6, l = tid & 63;
  if (l == 0) { s[w] = a; s[4 + w] = b; }
  __syncthreads();
  if (tid == 0) {
    out[B_SZ] = (s[0] + s[1] + s[2] + s[3]) * (1.f / 300.f);
    out[B_SZ + 1] = s[4] + s[5] + s[6] + s[7];
  }
}

extern "C" void kernel_launch(void* const* d_in, const int* in_sizes, int n_in,
                              void* d_out, int out_size, void* d_ws, size_t ws_size,
                              hipStream_t stream) {
  const float* inps = (const float*)d_in[0];
  const float* tw   = (const float*)d_in[1];
  const float* tb   = (const float*)d_in[2];
  const float* mw   = (const float*)d_in[3];
  float* out = (float*)d_out;
  float* wsf = (float*)d_ws;
  setup_kernel<<<50, 256, 0, stream>>>(mw, tw, wsf);
  main_kernel<<<256, 256, 0, stream>>>(inps, tb, wsf, out);
  reduce_kernel<<<1, 256, 0, stream>>>(wsf, out);
}